// Round 16
// baseline (333.062 us; speedup 1.0000x reference)
//
#include <hip/hip_runtime.h>
#include <hip/hip_bf16.h>

typedef __bf16 bf16_t;
typedef __bf16 bf16x8 __attribute__((ext_vector_type(8)));
typedef __bf16 bf16x4 __attribute__((ext_vector_type(4)));
typedef __bf16 bf16x2 __attribute__((ext_vector_type(2)));
typedef float  f32x4  __attribute__((ext_vector_type(4)));
typedef float  f32x16 __attribute__((ext_vector_type(16)));

#define NB 2
#define NS 2048
#define ND 2048
#define NH 16
#define QLORA 1536
#define KVLORA 512
#define DNOPE 128
#define DROPE 64
#define DVDIM 128
#define QKD 192

// 1/sqrt(192) * log2(e): Q is pre-scaled by this so QK^T lands in exp2 domain.
#define QSCALE 0.10411754f

#if __has_builtin(__builtin_amdgcn_exp2f)
#define EXP2F(x) __builtin_amdgcn_exp2f(x)
#else
#define EXP2F(x) __expf((x) * 0.69314718056f)
#endif
#if __has_builtin(__builtin_amdgcn_rcpf)
#define RCPF(x) __builtin_amdgcn_rcpf(x)
#else
#define RCPF(x) (1.0f / (x))
#endif

typedef __attribute__((address_space(3))) void as3_void;
typedef __attribute__((address_space(1))) const void as1_void;
__device__ __forceinline__ void gload16(const void* g, void* l) {
  __builtin_amdgcn_global_load_lds((as1_void*)g, (as3_void*)l, 16, 0, 0);
}

__device__ __forceinline__ int pack2(float a, float b) {
  bf16x2 t = {(bf16_t)a, (bf16_t)b};
  return __builtin_bit_cast(int, t);
}

// ---------------- fused f32 -> bf16 convert for all 6 tensors ----------------
__global__ __launch_bounds__(256) void k_cvt_all(
    const float* __restrict__ x, const float* __restrict__ wqa,
    const float* __restrict__ wqb, const float* __restrict__ wkva,
    const float* __restrict__ wkvb, const float* __restrict__ wo,
    bf16_t* __restrict__ xb, bf16_t* __restrict__ wqab, bf16_t* __restrict__ wqbb,
    bf16_t* __restrict__ wkvab, bf16_t* __restrict__ wkvbb, bf16_t* __restrict__ wob) {
  const int c0 = 2097152, c1 = 2883584, c2 = 4063232, c3 = 4358144, c4 = 4882432,
            c5 = 5931008;
  int i = blockIdx.x * 256 + threadIdx.x;
  for (; i < c5; i += gridDim.x * 256) {
    const float* src;
    bf16_t* dst;
    int off;
    if (i < c0) { src = x; dst = xb; off = i; }
    else if (i < c1) { src = wqa; dst = wqab; off = i - c0; }
    else if (i < c2) { src = wqb; dst = wqbb; off = i - c1; }
    else if (i < c3) { src = wkva; dst = wkvab; off = i - c2; }
    else if (i < c4) { src = wkvb; dst = wkvbb; off = i - c3; }
    else { src = wo; dst = wob; off = i - c4; }
    float4 v = reinterpret_cast<const float4*>(src)[off];
    bf16x4 o = {(bf16_t)v.x, (bf16_t)v.y, (bf16_t)v.z, (bf16_t)v.w};
    reinterpret_cast<bf16x4*>(dst)[off] = o;
  }
}

// ---------------- epilogue (shared by both cores) ----------------
template <int EPI>
__device__ __forceinline__ void gemm_epi(
    int col, int row0, const f32x4& a4,
    float* __restrict__ Cf, float* __restrict__ Cf2,
    bf16_t* __restrict__ Kout, bf16_t* __restrict__ Vtout,
    const float* __restrict__ fc, const float* __restrict__ fs, int N) {
  if (EPI == 1) {
    int h = col >> 8, rr = col & 255;
    int b = row0 >> 11, s0 = row0 & 2047;
    if (rr < DNOPE) {
#pragma unroll
      for (int r = 0; r < 4; ++r)
        Kout[(((size_t)(b * NH + h)) * NS + s0 + r) * QKD + rr] = (bf16_t)a4[r];
    } else {
      bf16x4 pv4 = {(bf16_t)a4[0], (bf16_t)a4[1], (bf16_t)a4[2], (bf16_t)a4[3]};
      *reinterpret_cast<bf16x4*>(
          &Vtout[(((size_t)(b * NH + h)) * DVDIM + (rr - DNOPE)) * NS + s0]) = pv4;
    }
  } else {
#pragma unroll
    for (int r = 0; r < 4; ++r) {
      int row = row0 + r;
      float v = a4[r];
      if (EPI == 0) {
        Cf[(size_t)row * N + col] = v;
      } else if (EPI == 2) {
        int h = col / 192;
        int d = col - h * 192;
        int b = row >> 11, s = row & 2047;
        float y = v;
        if (d >= DNOPE) {
          float pv = __shfl_xor(v, 1);
          int pp = ((d & ~1) - DNOPE) >> 1;
          float c = fc[s * 32 + pp], si = fs[s * 32 + pp];
          y = (col & 1) ? (pv * si + v * c) : (v * c - pv * si);
        }
        Kout[((size_t)(b * NH + h) * NS + s) * QKD + d] = (bf16_t)(y * QSCALE);
      } else {  // EPI 3
        if (col < QLORA) Cf[(size_t)row * QLORA + col] = v;
        else if (col < QLORA + KVLORA + DROPE)
          Cf2[(size_t)row * (KVLORA + DROPE) + (col - QLORA)] = v;
      }
    }
  }
}

// ---------------- GEMM core 128x128 (4 waves, r10-proven) ----------------
template <int EPI>
__device__ __forceinline__ void gemm_core(
    int rank, bf16_t* As, bf16_t* Bs,
    const bf16_t* __restrict__ A, const bf16_t* __restrict__ Bw,
    float* __restrict__ Cf, float* __restrict__ Cf2,
    bf16_t* __restrict__ Kout, bf16_t* __restrict__ Vtout,
    const float* __restrict__ fc, const float* __restrict__ fs,
    int M, int N, int K) {
  const int tid = threadIdx.x;
  const int lane = tid & 63;
  const int wave = tid >> 6;
  const int wm = (wave >> 1) * 64, wn = (wave & 1) * 64;
  const int nxt = (N + 127) >> 7;
  const int by = rank / nxt, bx = rank - by * nxt;
  const int m0 = by * 128, n0 = bx * 128;
  const int l15 = lane & 15, l4 = lane >> 4;
  const int srow = lane >> 3;
  const int scol = ((lane & 7) ^ srow) * 8;

  const f32x4 Z4 = {0.f, 0.f, 0.f, 0.f};
  f32x4 acc[4][4];
#pragma unroll
  for (int i = 0; i < 4; ++i)
#pragma unroll
    for (int j = 0; j < 4; ++j) acc[i][j] = Z4;

  auto stage = [&](int buf, int k0) {
#pragma unroll
    for (int c = 0; c < 4; ++c) {
      int chunk = c * 4 + wave;
      int row = chunk * 8 + srow;
      gload16(A + (size_t)(m0 + row) * K + k0 + scol, &As[buf * 8192 + chunk * 512]);
      gload16(Bw + (size_t)(n0 + row) * K + k0 + scol, &Bs[buf * 8192 + chunk * 512]);
    }
  };

  const int nk = K >> 6;
  stage(0, 0);
  int cur = 0;
#pragma unroll 1
  for (int t = 0; t < nk; ++t) {
    if (t + 1 < nk) {
      stage(cur ^ 1, (t + 1) * 64);
      asm volatile("s_waitcnt vmcnt(8)" ::: "memory");
    } else {
      asm volatile("s_waitcnt vmcnt(0)" ::: "memory");
    }
    __builtin_amdgcn_sched_barrier(0);
    __builtin_amdgcn_s_barrier();
    __builtin_amdgcn_sched_barrier(0);
#pragma unroll
    for (int ks = 0; ks < 2; ++ks) {
      int kc = ks * 4 + l4;
      int pc = (kc ^ (l15 & 7)) * 8;
      bf16x8 af[4], bfr[4];
#pragma unroll
      for (int f = 0; f < 4; ++f) {
        af[f] = *reinterpret_cast<const bf16x8*>(
            &As[cur * 8192 + (wm + f * 16 + l15) * 64 + pc]);
        bfr[f] = *reinterpret_cast<const bf16x8*>(
            &Bs[cur * 8192 + (wn + f * 16 + l15) * 64 + pc]);
      }
#pragma unroll
      for (int fi = 0; fi < 4; ++fi)
#pragma unroll
        for (int fj = 0; fj < 4; ++fj)
          acc[fi][fj] = __builtin_amdgcn_mfma_f32_16x16x32_bf16(af[fi], bfr[fj], acc[fi][fj], 0, 0, 0);
    }
    __builtin_amdgcn_sched_barrier(0);
    __builtin_amdgcn_s_barrier();
    cur ^= 1;
  }

#pragma unroll
  for (int fi = 0; fi < 4; ++fi)
#pragma unroll
    for (int fj = 0; fj < 4; ++fj)
      gemm_epi<EPI>(n0 + wn + fj * 16 + l15, m0 + wm + fi * 16 + l4 * 4, acc[fi][fj],
                    Cf, Cf2, Kout, Vtout, fc, fs, N);
}

// ---------------- GEMM core 256Mx128N (8 waves / 512 thr, same structure) ----
// Staging bytes/FLOP 1.5 vs 2.0 at 128^2; per-wave inner loop identical.
template <int EPI>
__device__ __forceinline__ void gemm_core256(
    int rank, bf16_t* As, bf16_t* Bs,
    const bf16_t* __restrict__ A, const bf16_t* __restrict__ Bw,
    bf16_t* __restrict__ Kout, bf16_t* __restrict__ Vtout,
    const float* __restrict__ fc, const float* __restrict__ fs,
    int N, int K) {
  const int tid = threadIdx.x;
  const int lane = tid & 63;
  const int wave = tid >> 6;  // 0..7
  const int wm = (wave >> 1) * 64;  // 0..192 (M within 256)
  const int wn = (wave & 1) * 64;   // 0,64   (N within 128)
  const int nxt = N >> 7;
  const int by = rank / nxt, bx = rank - by * nxt;
  const int m0 = by * 256, n0 = bx * 128;
  const int l15 = lane & 15, l4 = lane >> 4;
  const int srow = lane >> 3;
  const int scol = ((lane & 7) ^ srow) * 8;

  const f32x4 Z4 = {0.f, 0.f, 0.f, 0.f};
  f32x4 acc[4][4];
#pragma unroll
  for (int i = 0; i < 4; ++i)
#pragma unroll
    for (int j = 0; j < 4; ++j) acc[i][j] = Z4;

  auto stage = [&](int buf, int k0) {
#pragma unroll
    for (int a = 0; a < 4; ++a) {  // A: 32 chunks of 8 rows (256 rows)
      int chunk = a * 8 + wave;
      int row = chunk * 8 + srow;
      gload16(A + (size_t)(m0 + row) * K + k0 + scol, &As[buf * 16384 + chunk * 512]);
    }
#pragma unroll
    for (int bq = 0; bq < 2; ++bq) {  // B: 16 chunks (128 rows)
      int chunk = bq * 8 + wave;
      int row = chunk * 8 + srow;
      gload16(Bw + (size_t)(n0 + row) * K + k0 + scol, &Bs[buf * 8192 + chunk * 512]);
    }
  };

  const int nk = K >> 6;
  stage(0, 0);
  int cur = 0;
#pragma unroll 1
  for (int t = 0; t < nk; ++t) {
    if (t + 1 < nk) {
      stage(cur ^ 1, (t + 1) * 64);
      asm volatile("s_waitcnt vmcnt(6)" ::: "memory");
    } else {
      asm volatile("s_waitcnt vmcnt(0)" ::: "memory");
    }
    __builtin_amdgcn_sched_barrier(0);
    __builtin_amdgcn_s_barrier();
    __builtin_amdgcn_sched_barrier(0);
#pragma unroll
    for (int ks = 0; ks < 2; ++ks) {
      int kc = ks * 4 + l4;
      int pc = (kc ^ (l15 & 7)) * 8;
      bf16x8 af[4], bfr[4];
#pragma unroll
      for (int f = 0; f < 4; ++f) {
        af[f] = *reinterpret_cast<const bf16x8*>(
            &As[cur * 16384 + (wm + f * 16 + l15) * 64 + pc]);
        bfr[f] = *reinterpret_cast<const bf16x8*>(
            &Bs[cur * 8192 + (wn + f * 16 + l15) * 64 + pc]);
      }
#pragma unroll
      for (int fi = 0; fi < 4; ++fi)
#pragma unroll
        for (int fj = 0; fj < 4; ++fj)
          acc[fi][fj] = __builtin_amdgcn_mfma_f32_16x16x32_bf16(af[fi], bfr[fj], acc[fi][fj], 0, 0, 0);
    }
    __builtin_amdgcn_sched_barrier(0);
    __builtin_amdgcn_s_barrier();
    cur ^= 1;
  }

#pragma unroll
  for (int fi = 0; fi < 4; ++fi)
#pragma unroll
    for (int fj = 0; fj < 4; ++fj)
      gemm_epi<EPI>(n0 + wn + fj * 16 + l15, m0 + wm + fi * 16 + l4 * 4, acc[fi][fj],
                    nullptr, nullptr, Kout, Vtout, fc, fs, N);
}

// standalone GEMM wrapper (128^2, XCD-chunked swizzle)
template <int EPI>
__global__ __launch_bounds__(256) void k_gemm_bt(
    const bf16_t* __restrict__ A, const bf16_t* __restrict__ Bw,
    float* __restrict__ Cf, float* __restrict__ Cf2,
    bf16_t* __restrict__ Kout, bf16_t* __restrict__ Vtout,
    const float* __restrict__ fc, const float* __restrict__ fs,
    int M, int N, int K) {
  __shared__ bf16_t As[2 * 128 * 64];
  __shared__ bf16_t Bs[2 * 128 * 64];
  const int per = gridDim.x >> 3;
  const int rank = (blockIdx.x & 7) * per + (blockIdx.x >> 3);
  gemm_core<EPI>(rank, As, Bs, A, Bw, Cf, Cf2, Kout, Vtout, fc, fs, M, N, K);
}

// dual GEMM, 256Mx128N tiles, 512 threads: blocks [0,384) -> wq_b (EPI2);
// [384,896) -> kv_b (EPI1). 96KB LDS, 8 waves/CU.
__global__ __launch_bounds__(512) void k_gemm_dual(
    const bf16_t* __restrict__ A2, const bf16_t* __restrict__ B2,
    bf16_t* __restrict__ Qb, const float* __restrict__ fc,
    const float* __restrict__ fs, const bf16_t* __restrict__ A1,
    const bf16_t* __restrict__ B1, bf16_t* __restrict__ Kout,
    bf16_t* __restrict__ Vtout) {
  __shared__ bf16_t As[2 * 256 * 64];
  __shared__ bf16_t Bs[2 * 128 * 64];
  const int G2 = 384;  // wq_b tiles: 16 x 24
  if ((int)blockIdx.x < G2) {
    int id = blockIdx.x;
    int rank = (id & 7) * (G2 >> 3) + (id >> 3);
    gemm_core256<2>(rank, As, Bs, A2, B2, Qb, nullptr, fc, fs, NH * QKD, QLORA);
  } else {
    int id = blockIdx.x - G2;  // 512 tiles: 16 x 32
    int rank = (id & 7) * 64 + (id >> 3);
    gemm_core256<1>(rank, As, Bs, A1, B1, Kout, Vtout, nullptr, nullptr,
                    NH * (DNOPE + DVDIM), KVLORA);
  }
}

// ---------------- merged per-token post: RMS-norm(q_a) + RMS-norm(kv)+RoPE ----
__global__ __launch_bounds__(256) void k_norm_post(
    const float* __restrict__ qa, const float* __restrict__ qw,
    bf16_t* __restrict__ qan, const float* __restrict__ kvf,
    const float* __restrict__ kw, const float* __restrict__ fc,
    const float* __restrict__ fs, bf16_t* __restrict__ kvn,
    bf16_t* __restrict__ Kb) {
  int row = blockIdx.x;  // token
  __shared__ float red[4];
  {
    const float* rp = qa + (size_t)row * QLORA;
    float ss = 0.f;
    for (int c = threadIdx.x * 4; c < QLORA; c += 1024) {
      float4 v = *reinterpret_cast<const float4*>(rp + c);
      ss += v.x * v.x + v.y * v.y + v.z * v.z + v.w * v.w;
    }
#pragma unroll
    for (int m = 32; m; m >>= 1) ss += __shfl_xor(ss, m);
    if ((threadIdx.x & 63) == 0) red[threadIdx.x >> 6] = ss;
    __syncthreads();
    float tot = red[0] + red[1] + red[2] + red[3];
    float rs = rsqrtf(tot / (float)QLORA + 1e-6f);
    for (int c = threadIdx.x * 4; c < QLORA; c += 1024) {
      float4 v = *reinterpret_cast<const float4*>(rp + c);
      bf16x4 o = {(bf16_t)(v.x * rs * qw[c]), (bf16_t)(v.y * rs * qw[c + 1]),
                  (bf16_t)(v.z * rs * qw[c + 2]), (bf16_t)(v.w * rs * qw[c + 3])};
      *reinterpret_cast<bf16x4*>(qan + (size_t)row * QLORA + c) = o;
    }
  }
  __syncthreads();
  const float* rp = kvf + (size_t)row * (KVLORA + DROPE);
  float ss = 0.f;
  float4 v = {0.f, 0.f, 0.f, 0.f};
  if (threadIdx.x < 128) {
    v = reinterpret_cast<const float4*>(rp)[threadIdx.x];
    ss = v.x * v.x + v.y * v.y + v.z * v.z + v.w * v.w;
  }
#pragma unroll
  for (int m = 32; m; m >>= 1) ss += __shfl_xor(ss, m);
  if ((threadIdx.x & 63) == 0) red[threadIdx.x >> 6] = ss;
  __syncthreads();
  float tot = red[0] + red[1] + red[2] + red[3];
  float rs = rsqrtf(tot / (float)KVLORA + 1e-6f);
  if (threadIdx.x < 128) {
    int c = threadIdx.x * 4;
    bf16x4 o = {(bf16_t)(v.x * rs * kw[c]), (bf16_t)(v.y * rs * kw[c + 1]),
                (bf16_t)(v.z * rs * kw[c + 2]), (bf16_t)(v.w * rs * kw[c + 3])};
    *reinterpret_cast<bf16x4*>(kvn + (size_t)row * KVLORA + c) = o;
  }
  int b = row >> 11, s = row & 2047;
  if (threadIdx.x < 32) {
    int p = threadIdx.x;
    float x0 = rp[KVLORA + 2 * p], x1 = rp[KVLORA + 2 * p + 1];
    float c = fc[s * 32 + p], si = fs[s * 32 + p];
    float yr = x0 * c - x1 * si, yi = x0 * si + x1 * c;
    bf16_t br = (bf16_t)yr, bi = (bf16_t)yi;
    for (int h = 0; h < NH; ++h) {
      size_t ob = ((size_t)(b * NH + h) * NS + s) * QKD + DNOPE;
      Kb[ob + 2 * p] = br;
      Kb[ob + 2 * p + 1] = bi;
    }
  }
}

// ---------------- flash attention: 32x32 MFMA, swapped QK^T, in-register softmax ----
// r11-exact (proven 94us): 4 waves x 32 q (QBLK=128), KVBLK=64, K/V dbuf LDS 80KB,
// gload_lds prefetch + counted vmcnt(10) + raw s_barriers. At LDS-BW cap (~19%).
__global__ __launch_bounds__(256, 2) void k_attn(const bf16_t* __restrict__ Qb,
                                                 const bf16_t* __restrict__ Kb,
                                                 const bf16_t* __restrict__ Vtb,
                                                 bf16_t* __restrict__ Ao) {
  __shared__ bf16x8 Ks8[2][64 * 24];
  __shared__ bf16x8 Vs8[2][128 * 8];
  const int id = blockIdx.x;
  const int bh = id & 31;
  const int aa = (id >> 5) & 7;
  const int qt = (id >> 8) ? aa : (15 - aa);
  const int b = bh >> 4, h = bh & 15;
  const int tid = threadIdx.x;
  const int lane = tid & 63, wave = tid >> 6;
  const int l31 = lane & 31, hi = lane >> 5;
  const int q0w = qt * 128 + wave * 32;
  const int qg = q0w + l31;  // this lane's q row
  const int c4 = hi * 4;
  const int ntiles = 2 * qt + 2;
  const size_t bhNS = (size_t)bh * NS;

  const bf16_t* KbB = Kb + bhNS * QKD;
  const bf16_t* VtB = Vtb + (size_t)bh * DVDIM * NS;
  int koff[6], voff[4];
#pragma unroll
  for (int i = 0; i < 6; ++i) {
    int p = tid + i * 256;
    int row = p / 24, pc = p % 24;
    int lc = (pc & ~7) | ((pc ^ row) & 7);
    koff[i] = row * QKD + lc * 8;
  }
#pragma unroll
  for (int i = 0; i < 4; ++i) {
    int p = tid + i * 256;
    int row = p >> 3, pc = p & 7;
    int lc = pc ^ (row & 7);
    voff[i] = row * NS + lc * 8;
  }

  auto stageKV = [&](int buf, int kv0) {
    const bf16_t* ksrc = KbB + kv0 * QKD;
    const bf16_t* vsrc = VtB + kv0;
    bf16x8* kdst = &Ks8[buf][wave * 64];
    bf16x8* vdst = &Vs8[buf][wave * 64];
#pragma unroll
    for (int i = 0; i < 6; ++i) gload16(ksrc + koff[i], kdst + i * 256);
#pragma unroll
    for (int i = 0; i < 4; ++i) gload16(vsrc + voff[i], vdst + i * 256);
  };

  bf16x8 qf[12];
  {
    const bf16_t* qp = Qb + (bhNS + qg) * QKD + hi * 8;
#pragma unroll
    for (int ks = 0; ks < 12; ++ks)
      qf[ks] = *reinterpret_cast<const bf16x8*>(qp + ks * 16);
  }

  f32x16 oacc[4];
#pragma unroll
  for (int d = 0; d < 4; ++d) oacc[d] = {};
  float mrun = -3e38f, lrun = 0.f;

  stageKV(0, 0);
  int cur = 0;

#pragma unroll 1
  for (int kt = 0; kt < ntiles; ++kt) {
    const int kv0 = kt * 64;
    if (kt + 1 < ntiles) {
      stageKV(cur ^ 1, kv0 + 64);
      asm volatile("s_waitcnt vmcnt(10)" ::: "memory");
    } else {
      asm volatile("s_waitcnt vmcnt(0)" ::: "memory");
    }
    __builtin_amdgcn_sched_barrier(0);
    __builtin_amdgcn_s_barrier();  // all waves: tile kt resident in LDS[cur]
    __builtin_amdgcn_sched_barrier(0);

    if (kv0 <= q0w + 31) {
      f32x16 sacc[2];
      sacc[0] = {};
      sacc[1] = {};
#pragma unroll
      for (int ks = 0; ks < 12; ++ks) {
#pragma unroll
        for (int kh = 0; kh < 2; ++kh) {
          int row = kh * 32 + l31;
          int c = ks * 2 + hi;
          int pc = (c & ~7) | ((c ^ row) & 7);
          sacc[kh] = __builtin_amdgcn_mfma_f32_32x32x16_bf16(Ks8[cur][row * 24 + pc],
                                                             qf[ks], sacc[kh], 0, 0, 0);
        }
      }

      const bool diag = (kv0 + 63 > q0w);
      float mloc = -3e38f;
#pragma unroll
      for (int kh = 0; kh < 2; ++kh)
#pragma unroll
        for (int rg = 0; rg < 16; ++rg) {
          float s = sacc[kh][rg];
          if (diag) {
            int kg = kv0 + kh * 32 + (rg & 3) + 8 * (rg >> 2) + c4;
            if (kg > qg) s = -3e38f;
            sacc[kh][rg] = s;
          }
          mloc = fmaxf(mloc, s);
        }
      mloc = fmaxf(mloc, __shfl_xor(mloc, 32));

      if (!__all(mloc <= mrun)) {
        float mn = fmaxf(mrun, mloc);
        float fac = EXP2F(mrun - mn);
        mrun = mn;
        lrun *= fac;
#pragma unroll
        for (int d = 0; d < 4; ++d)
#pragma unroll
          for (int rg = 0; rg < 16; ++rg) oacc[d][rg] *= fac;
      }

      float rsum = 0.f;
      int W[8][2];
#pragma unroll
      for (int kh = 0; kh < 2; ++kh)
#pragma unroll
        for (int g = 0; g < 4; ++g) {
          float p0 = EXP2F(sacc[kh][4 * g + 0] - mrun);
          float p1 = EXP2F(sacc[kh][4 * g + 1] - mrun);
          float p2 = EXP2F(sacc[kh][4 * g + 2] - mrun);
          float p3 = EXP2F(sacc[kh][4 * g + 3] - mrun);
          rsum += (p0 + p1) + (p2 + p3);
          W[kh * 4 + g][0] = pack2(p0, p1);
          W[kh * 4 + g][1] = pack2(p2, p3);
        }
      rsum += __shfl_xor(rsum, 32);
      lrun += rsum;

      bf16x8 pa[4];
#pragma unroll
      for (int pks = 0; pks < 4; ++pks) {
        int kh = pks >> 1, G0 = (pks & 1) * 2;
        int a0 = W[kh * 4 + G0][0], a1 = W[kh * 4 + G0][1];
        int b0 = W[kh * 4 + G0 + 1][0], b1 = W[kh * 4 + G0 + 1][1];
        int own0 = hi ? b0 : a0, own1 = hi ? b1 : a1;
        int oth0 = hi ? a0 : b0, oth1 = hi ? a1 : b1;
        int rc0 = __shfl_xor(oth0, 32), rc1 = __shfl_xor(oth1, 32);
        int4 wv;
        wv.x = hi ? rc0 : own0;
        wv.y = hi ? rc1 : own1;
        wv.z = hi ? own0 : rc0;
        wv.w = hi ? own1 : rc1;
        pa[pks] = __builtin_bit_cast(bf16x8, wv);
      }

#pragma unroll
      for (int pks = 0; pks < 4; ++pks)
#pragma unroll
        for (int dvt = 0; dvt < 4; ++dvt) {
          int row = dvt * 32 + l31;
          int pc = (pks * 2 + hi) ^ (row & 7);
          oacc[dvt] = __builtin_amdgcn_mfma_f32_32x32x16_bf16(Vs8[cur][row * 8 + pc],
                                                              pa[pks], oacc[dvt], 0, 0, 0);
        }
    }

    __builtin_amdgcn_sched_barrier(0);
    __builtin_amdgcn_s_barrier();  // all waves done reading LDS[cur]
    cur ^= 1;
  }

  // epilogue: O^T -> Ao[token][h*128+dv]
  float lr = RCPF(lrun);
  bf16_t* base = Ao + ((size_t)(b * NS) + qg) * (NH * DVDIM) + h * DVDIM;
#pragma unroll
  for (int dvt = 0; dvt < 4; ++dvt)
#pragma unroll
    for (int rg4 = 0; rg4 < 4; ++rg4) {
      int dv0 = dvt * 32 + 8 * rg4 + c4;
      bf16x4 o = {(bf16_t)(oacc[dvt][rg4 * 4 + 0] * lr),
                  (bf16_t)(oacc[dvt][rg4 * 4 + 1] * lr),
                  (bf16_t)(oacc[dvt][rg4 * 4 + 2] * lr),
                  (bf16_t)(oacc[dvt][rg4 * 4 + 3] * lr)};
      *reinterpret_cast<bf16x4*>(base + dv0) = o;
    }
}

// ---------------- launch ----------------
extern "C" void kernel_launch(void* const* d_in, const int* in_sizes, int n_in,
                              void* d_out, int out_size, void* d_ws, size_t ws_size,
                              hipStream_t stream) {
  (void)in_sizes; (void)n_in; (void)out_size; (void)ws_size;
  const float* x = (const float*)d_in[0];
  const float* fcos = (const float*)d_in[1];
  const float* fsin = (const float*)d_in[2];
  const float* wq_a = (const float*)d_in[4];
  const float* q_norm_w = (const float*)d_in[5];
  const float* wq_b = (const float*)d_in[6];
  const float* wkv_a = (const float*)d_in[7];
  const float* kv_norm_w = (const float*)d_in[8];
  const float* wkv_b = (const float*)d_in[9];
  const float* wo = (const float*)d_in[10];
  float* out = (float*)d_out;

  char* p = (char*)d_ws;
  bf16_t* x_bf = (bf16_t*)(p);
  bf16_t* wqa_bf = (bf16_t*)(p + 16777216);
  bf16_t* wkva_bf = (bf16_t*)(p + 23068672);  // contiguous with wqa
  bf16_t* wqb_bf = (bf16_t*)(p + 25427968);
  bf16_t* wkvb_bf = (bf16_t*)(p + 34865152);
  bf16_t* wo_bf = (bf16_t*)(p + 39059456);
  float* qa_f32 = (float*)(p + 47448064);
  bf16_t* Kb = (bf16_t*)(p + 47448064);  // union with qa_f32
  bf16_t* qan_bf = (bf16_t*)(p + 72613888);
  bf16_t* Qb = (bf16_t*)(p + 85196800);
  char* r2 = p + 110362624;
  float* kvf_f32 = (float*)(r2);
  bf16_t* kvn_bf = (bf16_t*)(r2 + 9437184);
  bf16_t* Vtb = (bf16_t*)(r2 + 13631488);
  bf16_t* attn_bf = (bf16_t*)(r2 + 30408704);

  k_cvt_all<<<2048, 256, 0, stream>>>(x, wq_a, wq_b, wkv_a, wkv_b, wo, x_bf, wqa_bf,
                                      wqb_bf, wkva_bf, wkvb_bf, wo_bf);

  // merged: [q_a | kv_full] = x @ [wq_a; wkv_a]^T  [4096, 2112]  (17x32 tiles)
  k_gemm_bt<3><<<dim3(544), 256, 0, stream>>>(x_bf, wqa_bf, qa_f32, kvf_f32,
                                              nullptr, nullptr, nullptr, nullptr,
                                              NB * NS, QLORA + KVLORA + DROPE, ND);
  k_norm_post<<<NB * NS, 256, 0, stream>>>(qa_f32, q_norm_w, qan_bf, kvf_f32,
                                           kv_norm_w, fcos, fsin, kvn_bf, Kb);
  // dual (256Mx128N, 512 thr): wq_b (RoPE -> Qb) + kv_b (K-nope + V^T)
  k_gemm_dual<<<dim3(896), 512, 0, stream>>>(qan_bf, wqb_bf, Qb, fcos, fsin,
                                             kvn_bf, wkvb_bf, Kb, Vtb);
  // attention: 512 blocks x 256 threads, longest-first constant-sum pairing
  k_attn<<<dim3(512), 256, 0, stream>>>(Qb, Kb, Vtb, attn_bf);
  // out = attn @ wo^T  [4096,2048] f32  (16x32 tiles)
  k_gemm_bt<0><<<dim3(512), 256, 0, stream>>>(attn_bf, wo_bf, out, nullptr, nullptr,
                                              nullptr, nullptr, nullptr, NB * NS, ND,
                                              NH * DVDIM);
}

// Round 17
// 322.088 us; speedup vs baseline: 1.0341x; 1.0341x over previous
//
#include <hip/hip_runtime.h>
#include <hip/hip_bf16.h>

typedef __bf16 bf16_t;
typedef __bf16 bf16x8 __attribute__((ext_vector_type(8)));
typedef __bf16 bf16x4 __attribute__((ext_vector_type(4)));
typedef __bf16 bf16x2 __attribute__((ext_vector_type(2)));
typedef float  f32x4  __attribute__((ext_vector_type(4)));
typedef float  f32x16 __attribute__((ext_vector_type(16)));

#define NB 2
#define NS 2048
#define ND 2048
#define NH 16
#define QLORA 1536
#define KVLORA 512
#define DNOPE 128
#define DROPE 64
#define DVDIM 128
#define QKD 192

// 1/sqrt(192) * log2(e): Q is pre-scaled by this so QK^T lands in exp2 domain.
#define QSCALE 0.10411754f

#if __has_builtin(__builtin_amdgcn_exp2f)
#define EXP2F(x) __builtin_amdgcn_exp2f(x)
#else
#define EXP2F(x) __expf((x) * 0.69314718056f)
#endif
#if __has_builtin(__builtin_amdgcn_rcpf)
#define RCPF(x) __builtin_amdgcn_rcpf(x)
#else
#define RCPF(x) (1.0f / (x))
#endif

typedef __attribute__((address_space(3))) void as3_void;
typedef __attribute__((address_space(1))) const void as1_void;
__device__ __forceinline__ void gload16(const void* g, void* l) {
  __builtin_amdgcn_global_load_lds((as1_void*)g, (as3_void*)l, 16, 0, 0);
}

__device__ __forceinline__ int pack2(float a, float b) {
  bf16x2 t = {(bf16_t)a, (bf16_t)b};
  return __builtin_bit_cast(int, t);
}

// ---------------- fused f32 -> bf16 convert for all 6 tensors ----------------
__global__ __launch_bounds__(256) void k_cvt_all(
    const float* __restrict__ x, const float* __restrict__ wqa,
    const float* __restrict__ wqb, const float* __restrict__ wkva,
    const float* __restrict__ wkvb, const float* __restrict__ wo,
    bf16_t* __restrict__ xb, bf16_t* __restrict__ wqab, bf16_t* __restrict__ wqbb,
    bf16_t* __restrict__ wkvab, bf16_t* __restrict__ wkvbb, bf16_t* __restrict__ wob) {
  const int c0 = 2097152, c1 = 2883584, c2 = 4063232, c3 = 4358144, c4 = 4882432,
            c5 = 5931008;
  int i = blockIdx.x * 256 + threadIdx.x;
  for (; i < c5; i += gridDim.x * 256) {
    const float* src;
    bf16_t* dst;
    int off;
    if (i < c0) { src = x; dst = xb; off = i; }
    else if (i < c1) { src = wqa; dst = wqab; off = i - c0; }
    else if (i < c2) { src = wqb; dst = wqbb; off = i - c1; }
    else if (i < c3) { src = wkva; dst = wkvab; off = i - c2; }
    else if (i < c4) { src = wkvb; dst = wkvbb; off = i - c3; }
    else { src = wo; dst = wob; off = i - c4; }
    float4 v = reinterpret_cast<const float4*>(src)[off];
    bf16x4 o = {(bf16_t)v.x, (bf16_t)v.y, (bf16_t)v.z, (bf16_t)v.w};
    reinterpret_cast<bf16x4*>(dst)[off] = o;
  }
}

// ---------------- epilogue (shared) ----------------
template <int EPI>
__device__ __forceinline__ void gemm_epi(
    int col, int row0, const f32x4& a4,
    float* __restrict__ Cf, float* __restrict__ Cf2,
    bf16_t* __restrict__ Kout, bf16_t* __restrict__ Vtout,
    const float* __restrict__ fc, const float* __restrict__ fs, int N) {
  if (EPI == 1) {
    int h = col >> 8, rr = col & 255;
    int b = row0 >> 11, s0 = row0 & 2047;
    if (rr < DNOPE) {
#pragma unroll
      for (int r = 0; r < 4; ++r)
        Kout[(((size_t)(b * NH + h)) * NS + s0 + r) * QKD + rr] = (bf16_t)a4[r];
    } else {
      bf16x4 pv4 = {(bf16_t)a4[0], (bf16_t)a4[1], (bf16_t)a4[2], (bf16_t)a4[3]};
      *reinterpret_cast<bf16x4*>(
          &Vtout[(((size_t)(b * NH + h)) * DVDIM + (rr - DNOPE)) * NS + s0]) = pv4;
    }
  } else {
#pragma unroll
    for (int r = 0; r < 4; ++r) {
      int row = row0 + r;
      float v = a4[r];
      if (EPI == 0) {
        Cf[(size_t)row * N + col] = v;
      } else if (EPI == 2) {
        int h = col / 192;
        int d = col - h * 192;
        int b = row >> 11, s = row & 2047;
        float y = v;
        if (d >= DNOPE) {
          float pv = __shfl_xor(v, 1);
          int pp = ((d & ~1) - DNOPE) >> 1;
          float c = fc[s * 32 + pp], si = fs[s * 32 + pp];
          y = (col & 1) ? (pv * si + v * c) : (v * c - pv * si);
        }
        Kout[((size_t)(b * NH + h) * NS + s) * QKD + d] = (bf16_t)(y * QSCALE);
      } else {  // EPI 3
        if (col < QLORA) Cf[(size_t)row * QLORA + col] = v;
        else if (col < QLORA + KVLORA + DROPE)
          Cf2[(size_t)row * (KVLORA + DROPE) + (col - QLORA)] = v;
      }
    }
  }
}

// ---------------- GEMM core 128x128 (4 waves, r10-proven; 64KB -> 2 blocks/CU) ----
template <int EPI>
__device__ __forceinline__ void gemm_core(
    int rank, bf16_t* As, bf16_t* Bs,
    const bf16_t* __restrict__ A, const bf16_t* __restrict__ Bw,
    float* __restrict__ Cf, float* __restrict__ Cf2,
    bf16_t* __restrict__ Kout, bf16_t* __restrict__ Vtout,
    const float* __restrict__ fc, const float* __restrict__ fs,
    int M, int N, int K) {
  const int tid = threadIdx.x;
  const int lane = tid & 63;
  const int wave = tid >> 6;
  const int wm = (wave >> 1) * 64, wn = (wave & 1) * 64;
  const int nxt = (N + 127) >> 7;
  const int by = rank / nxt, bx = rank - by * nxt;
  const int m0 = by * 128, n0 = bx * 128;
  const int l15 = lane & 15, l4 = lane >> 4;
  const int srow = lane >> 3;
  const int scol = ((lane & 7) ^ srow) * 8;

  const f32x4 Z4 = {0.f, 0.f, 0.f, 0.f};
  f32x4 acc[4][4];
#pragma unroll
  for (int i = 0; i < 4; ++i)
#pragma unroll
    for (int j = 0; j < 4; ++j) acc[i][j] = Z4;

  auto stage = [&](int buf, int k0) {
#pragma unroll
    for (int c = 0; c < 4; ++c) {
      int chunk = c * 4 + wave;
      int row = chunk * 8 + srow;
      gload16(A + (size_t)(m0 + row) * K + k0 + scol, &As[buf * 8192 + chunk * 512]);
      gload16(Bw + (size_t)(n0 + row) * K + k0 + scol, &Bs[buf * 8192 + chunk * 512]);
    }
  };

  const int nk = K >> 6;
  stage(0, 0);
  int cur = 0;
#pragma unroll 1
  for (int t = 0; t < nk; ++t) {
    if (t + 1 < nk) {
      stage(cur ^ 1, (t + 1) * 64);
      asm volatile("s_waitcnt vmcnt(8)" ::: "memory");
    } else {
      asm volatile("s_waitcnt vmcnt(0)" ::: "memory");
    }
    __builtin_amdgcn_sched_barrier(0);
    __builtin_amdgcn_s_barrier();
    __builtin_amdgcn_sched_barrier(0);
#pragma unroll
    for (int ks = 0; ks < 2; ++ks) {
      int kc = ks * 4 + l4;
      int pc = (kc ^ (l15 & 7)) * 8;
      bf16x8 af[4], bfr[4];
#pragma unroll
      for (int f = 0; f < 4; ++f) {
        af[f] = *reinterpret_cast<const bf16x8*>(
            &As[cur * 8192 + (wm + f * 16 + l15) * 64 + pc]);
        bfr[f] = *reinterpret_cast<const bf16x8*>(
            &Bs[cur * 8192 + (wn + f * 16 + l15) * 64 + pc]);
      }
#pragma unroll
      for (int fi = 0; fi < 4; ++fi)
#pragma unroll
        for (int fj = 0; fj < 4; ++fj)
          acc[fi][fj] = __builtin_amdgcn_mfma_f32_16x16x32_bf16(af[fi], bfr[fj], acc[fi][fj], 0, 0, 0);
    }
    __builtin_amdgcn_sched_barrier(0);
    __builtin_amdgcn_s_barrier();
    cur ^= 1;
  }

#pragma unroll
  for (int fi = 0; fi < 4; ++fi)
#pragma unroll
    for (int fj = 0; fj < 4; ++fj)
      gemm_epi<EPI>(n0 + wn + fj * 16 + l15, m0 + wm + fi * 16 + l4 * 4, acc[fi][fj],
                    Cf, Cf2, Kout, Vtout, fc, fs, N);
}

// standalone GEMM wrapper (128^2, XCD-chunked swizzle)
template <int EPI>
__global__ __launch_bounds__(256) void k_gemm_bt(
    const bf16_t* __restrict__ A, const bf16_t* __restrict__ Bw,
    float* __restrict__ Cf, float* __restrict__ Cf2,
    bf16_t* __restrict__ Kout, bf16_t* __restrict__ Vtout,
    const float* __restrict__ fc, const float* __restrict__ fs,
    int M, int N, int K) {
  __shared__ bf16_t As[2 * 128 * 64];
  __shared__ bf16_t Bs[2 * 128 * 64];
  const int per = gridDim.x >> 3;
  const int rank = (blockIdx.x & 7) * per + (blockIdx.x >> 3);
  gemm_core<EPI>(rank, As, Bs, A, Bw, Cf, Cf2, Kout, Vtout, fc, fs, M, N, K);
}

// dual GEMM (r15-proven, 95us): blocks [0,768) -> wq_b (EPI2, fused RoPE);
// [768,1792) -> kv_b (EPI1). 128^2 tiles, 64KB LDS -> 2 blocks/CU.
__global__ __launch_bounds__(256) void k_gemm_dual(
    const bf16_t* __restrict__ A2, const bf16_t* __restrict__ B2,
    bf16_t* __restrict__ Qb, const float* __restrict__ fc,
    const float* __restrict__ fs, const bf16_t* __restrict__ A1,
    const bf16_t* __restrict__ B1, bf16_t* __restrict__ Kout,
    bf16_t* __restrict__ Vtout) {
  __shared__ bf16_t As[2 * 128 * 64];
  __shared__ bf16_t Bs[2 * 128 * 64];
  const int G2 = 768;  // wq_b tiles (32 x 24)
  if ((int)blockIdx.x < G2) {
    int id = blockIdx.x;
    int rank = (id & 7) * (G2 >> 3) + (id >> 3);
    gemm_core<2>(rank, As, Bs, A2, B2, nullptr, nullptr, Qb, nullptr, fc, fs,
                 NB * NS, NH * QKD, QLORA);
  } else {
    int id = blockIdx.x - G2;  // 1024 tiles (32 x 32)
    int rank = (id & 7) * 128 + (id >> 3);
    gemm_core<1>(rank, As, Bs, A1, B1, nullptr, nullptr, Kout, Vtout, nullptr,
                 nullptr, NB * NS, NH * (DNOPE + DVDIM), KVLORA);
  }
}

// ---------------- merged per-token post: RMS-norm(q_a) + RMS-norm(kv)+RoPE ----
__global__ __launch_bounds__(256) void k_norm_post(
    const float* __restrict__ qa, const float* __restrict__ qw,
    bf16_t* __restrict__ qan, const float* __restrict__ kvf,
    const float* __restrict__ kw, const float* __restrict__ fc,
    const float* __restrict__ fs, bf16_t* __restrict__ kvn,
    bf16_t* __restrict__ Kb) {
  int row = blockIdx.x;  // token
  __shared__ float red[4];
  {
    const float* rp = qa + (size_t)row * QLORA;
    float ss = 0.f;
    for (int c = threadIdx.x * 4; c < QLORA; c += 1024) {
      float4 v = *reinterpret_cast<const float4*>(rp + c);
      ss += v.x * v.x + v.y * v.y + v.z * v.z + v.w * v.w;
    }
#pragma unroll
    for (int m = 32; m; m >>= 1) ss += __shfl_xor(ss, m);
    if ((threadIdx.x & 63) == 0) red[threadIdx.x >> 6] = ss;
    __syncthreads();
    float tot = red[0] + red[1] + red[2] + red[3];
    float rs = rsqrtf(tot / (float)QLORA + 1e-6f);
    for (int c = threadIdx.x * 4; c < QLORA; c += 1024) {
      float4 v = *reinterpret_cast<const float4*>(rp + c);
      bf16x4 o = {(bf16_t)(v.x * rs * qw[c]), (bf16_t)(v.y * rs * qw[c + 1]),
                  (bf16_t)(v.z * rs * qw[c + 2]), (bf16_t)(v.w * rs * qw[c + 3])};
      *reinterpret_cast<bf16x4*>(qan + (size_t)row * QLORA + c) = o;
    }
  }
  __syncthreads();
  const float* rp = kvf + (size_t)row * (KVLORA + DROPE);
  float ss = 0.f;
  float4 v = {0.f, 0.f, 0.f, 0.f};
  if (threadIdx.x < 128) {
    v = reinterpret_cast<const float4*>(rp)[threadIdx.x];
    ss = v.x * v.x + v.y * v.y + v.z * v.z + v.w * v.w;
  }
#pragma unroll
  for (int m = 32; m; m >>= 1) ss += __shfl_xor(ss, m);
  if ((threadIdx.x & 63) == 0) red[threadIdx.x >> 6] = ss;
  __syncthreads();
  float tot = red[0] + red[1] + red[2] + red[3];
  float rs = rsqrtf(tot / (float)KVLORA + 1e-6f);
  if (threadIdx.x < 128) {
    int c = threadIdx.x * 4;
    bf16x4 o = {(bf16_t)(v.x * rs * kw[c]), (bf16_t)(v.y * rs * kw[c + 1]),
                (bf16_t)(v.z * rs * kw[c + 2]), (bf16_t)(v.w * rs * kw[c + 3])};
    *reinterpret_cast<bf16x4*>(kvn + (size_t)row * KVLORA + c) = o;
  }
  int b = row >> 11, s = row & 2047;
  if (threadIdx.x < 32) {
    int p = threadIdx.x;
    float x0 = rp[KVLORA + 2 * p], x1 = rp[KVLORA + 2 * p + 1];
    float c = fc[s * 32 + p], si = fs[s * 32 + p];
    float yr = x0 * c - x1 * si, yi = x0 * si + x1 * c;
    bf16_t br = (bf16_t)yr, bi = (bf16_t)yi;
    for (int h = 0; h < NH; ++h) {
      size_t ob = ((size_t)(b * NH + h) * NS + s) * QKD + DNOPE;
      Kb[ob + 2 * p] = br;
      Kb[ob + 2 * p + 1] = bi;
    }
  }
}

// ---------------- flash attention: 32x32 MFMA, swapped QK^T, in-register softmax ----
// r11-exact (proven 94us): 4 waves x 32 q (QBLK=128), KVBLK=64, K/V dbuf LDS 80KB,
// gload_lds prefetch + counted vmcnt(10) + raw s_barriers. At LDS-BW cap (~19%).
__global__ __launch_bounds__(256, 2) void k_attn(const bf16_t* __restrict__ Qb,
                                                 const bf16_t* __restrict__ Kb,
                                                 const bf16_t* __restrict__ Vtb,
                                                 bf16_t* __restrict__ Ao) {
  __shared__ bf16x8 Ks8[2][64 * 24];
  __shared__ bf16x8 Vs8[2][128 * 8];
  const int id = blockIdx.x;
  const int bh = id & 31;
  const int aa = (id >> 5) & 7;
  const int qt = (id >> 8) ? aa : (15 - aa);
  const int b = bh >> 4, h = bh & 15;
  const int tid = threadIdx.x;
  const int lane = tid & 63, wave = tid >> 6;
  const int l31 = lane & 31, hi = lane >> 5;
  const int q0w = qt * 128 + wave * 32;
  const int qg = q0w + l31;  // this lane's q row
  const int c4 = hi * 4;
  const int ntiles = 2 * qt + 2;
  const size_t bhNS = (size_t)bh * NS;

  const bf16_t* KbB = Kb + bhNS * QKD;
  const bf16_t* VtB = Vtb + (size_t)bh * DVDIM * NS;
  int koff[6], voff[4];
#pragma unroll
  for (int i = 0; i < 6; ++i) {
    int p = tid + i * 256;
    int row = p / 24, pc = p % 24;
    int lc = (pc & ~7) | ((pc ^ row) & 7);
    koff[i] = row * QKD + lc * 8;
  }
#pragma unroll
  for (int i = 0; i < 4; ++i) {
    int p = tid + i * 256;
    int row = p >> 3, pc = p & 7;
    int lc = pc ^ (row & 7);
    voff[i] = row * NS + lc * 8;
  }

  auto stageKV = [&](int buf, int kv0) {
    const bf16_t* ksrc = KbB + kv0 * QKD;
    const bf16_t* vsrc = VtB + kv0;
    bf16x8* kdst = &Ks8[buf][wave * 64];
    bf16x8* vdst = &Vs8[buf][wave * 64];
#pragma unroll
    for (int i = 0; i < 6; ++i) gload16(ksrc + koff[i], kdst + i * 256);
#pragma unroll
    for (int i = 0; i < 4; ++i) gload16(vsrc + voff[i], vdst + i * 256);
  };

  bf16x8 qf[12];
  {
    const bf16_t* qp = Qb + (bhNS + qg) * QKD + hi * 8;
#pragma unroll
    for (int ks = 0; ks < 12; ++ks)
      qf[ks] = *reinterpret_cast<const bf16x8*>(qp + ks * 16);
  }

  f32x16 oacc[4];
#pragma unroll
  for (int d = 0; d < 4; ++d) oacc[d] = {};
  float mrun = -3e38f, lrun = 0.f;

  stageKV(0, 0);
  int cur = 0;

#pragma unroll 1
  for (int kt = 0; kt < ntiles; ++kt) {
    const int kv0 = kt * 64;
    if (kt + 1 < ntiles) {
      stageKV(cur ^ 1, kv0 + 64);
      asm volatile("s_waitcnt vmcnt(10)" ::: "memory");
    } else {
      asm volatile("s_waitcnt vmcnt(0)" ::: "memory");
    }
    __builtin_amdgcn_sched_barrier(0);
    __builtin_amdgcn_s_barrier();  // all waves: tile kt resident in LDS[cur]
    __builtin_amdgcn_sched_barrier(0);

    if (kv0 <= q0w + 31) {
      f32x16 sacc[2];
      sacc[0] = {};
      sacc[1] = {};
#pragma unroll
      for (int ks = 0; ks < 12; ++ks) {
#pragma unroll
        for (int kh = 0; kh < 2; ++kh) {
          int row = kh * 32 + l31;
          int c = ks * 2 + hi;
          int pc = (c & ~7) | ((c ^ row) & 7);
          sacc[kh] = __builtin_amdgcn_mfma_f32_32x32x16_bf16(Ks8[cur][row * 24 + pc],
                                                             qf[ks], sacc[kh], 0, 0, 0);
        }
      }

      const bool diag = (kv0 + 63 > q0w);
      float mloc = -3e38f;
#pragma unroll
      for (int kh = 0; kh < 2; ++kh)
#pragma unroll
        for (int rg = 0; rg < 16; ++rg) {
          float s = sacc[kh][rg];
          if (diag) {
            int kg = kv0 + kh * 32 + (rg & 3) + 8 * (rg >> 2) + c4;
            if (kg > qg) s = -3e38f;
            sacc[kh][rg] = s;
          }
          mloc = fmaxf(mloc, s);
        }
      mloc = fmaxf(mloc, __shfl_xor(mloc, 32));

      if (!__all(mloc <= mrun)) {
        float mn = fmaxf(mrun, mloc);
        float fac = EXP2F(mrun - mn);
        mrun = mn;
        lrun *= fac;
#pragma unroll
        for (int d = 0; d < 4; ++d)
#pragma unroll
          for (int rg = 0; rg < 16; ++rg) oacc[d][rg] *= fac;
      }

      float rsum = 0.f;
      int W[8][2];
#pragma unroll
      for (int kh = 0; kh < 2; ++kh)
#pragma unroll
        for (int g = 0; g < 4; ++g) {
          float p0 = EXP2F(sacc[kh][4 * g + 0] - mrun);
          float p1 = EXP2F(sacc[kh][4 * g + 1] - mrun);
          float p2 = EXP2F(sacc[kh][4 * g + 2] - mrun);
          float p3 = EXP2F(sacc[kh][4 * g + 3] - mrun);
          rsum += (p0 + p1) + (p2 + p3);
          W[kh * 4 + g][0] = pack2(p0, p1);
          W[kh * 4 + g][1] = pack2(p2, p3);
        }
      rsum += __shfl_xor(rsum, 32);
      lrun += rsum;

      bf16x8 pa[4];
#pragma unroll
      for (int pks = 0; pks < 4; ++pks) {
        int kh = pks >> 1, G0 = (pks & 1) * 2;
        int a0 = W[kh * 4 + G0][0], a1 = W[kh * 4 + G0][1];
        int b0 = W[kh * 4 + G0 + 1][0], b1 = W[kh * 4 + G0 + 1][1];
        int own0 = hi ? b0 : a0, own1 = hi ? b1 : a1;
        int oth0 = hi ? a0 : b0, oth1 = hi ? a1 : b1;
        int rc0 = __shfl_xor(oth0, 32), rc1 = __shfl_xor(oth1, 32);
        int4 wv;
        wv.x = hi ? rc0 : own0;
        wv.y = hi ? rc1 : own1;
        wv.z = hi ? own0 : rc0;
        wv.w = hi ? own1 : rc1;
        pa[pks] = __builtin_bit_cast(bf16x8, wv);
      }

#pragma unroll
      for (int pks = 0; pks < 4; ++pks)
#pragma unroll
        for (int dvt = 0; dvt < 4; ++dvt) {
          int row = dvt * 32 + l31;
          int pc = (pks * 2 + hi) ^ (row & 7);
          oacc[dvt] = __builtin_amdgcn_mfma_f32_32x32x16_bf16(Vs8[cur][row * 8 + pc],
                                                              pa[pks], oacc[dvt], 0, 0, 0);
        }
    }

    __builtin_amdgcn_sched_barrier(0);
    __builtin_amdgcn_s_barrier();  // all waves done reading LDS[cur]
    cur ^= 1;
  }

  // epilogue: O^T -> Ao[token][h*128+dv]
  float lr = RCPF(lrun);
  bf16_t* base = Ao + ((size_t)(b * NS) + qg) * (NH * DVDIM) + h * DVDIM;
#pragma unroll
  for (int dvt = 0; dvt < 4; ++dvt)
#pragma unroll
    for (int rg4 = 0; rg4 < 4; ++rg4) {
      int dv0 = dvt * 32 + 8 * rg4 + c4;
      bf16x4 o = {(bf16_t)(oacc[dvt][rg4 * 4 + 0] * lr),
                  (bf16_t)(oacc[dvt][rg4 * 4 + 1] * lr),
                  (bf16_t)(oacc[dvt][rg4 * 4 + 2] * lr),
                  (bf16_t)(oacc[dvt][rg4 * 4 + 3] * lr)};
      *reinterpret_cast<bf16x4*>(base + dv0) = o;
    }
}

// ---------------- launch ----------------
extern "C" void kernel_launch(void* const* d_in, const int* in_sizes, int n_in,
                              void* d_out, int out_size, void* d_ws, size_t ws_size,
                              hipStream_t stream) {
  (void)in_sizes; (void)n_in; (void)out_size; (void)ws_size;
  const float* x = (const float*)d_in[0];
  const float* fcos = (const float*)d_in[1];
  const float* fsin = (const float*)d_in[2];
  const float* wq_a = (const float*)d_in[4];
  const float* q_norm_w = (const float*)d_in[5];
  const float* wq_b = (const float*)d_in[6];
  const float* wkv_a = (const float*)d_in[7];
  const float* kv_norm_w = (const float*)d_in[8];
  const float* wkv_b = (const float*)d_in[9];
  const float* wo = (const float*)d_in[10];
  float* out = (float*)d_out;

  char* p = (char*)d_ws;
  bf16_t* x_bf = (bf16_t*)(p);
  bf16_t* wqa_bf = (bf16_t*)(p + 16777216);
  bf16_t* wkva_bf = (bf16_t*)(p + 23068672);  // contiguous with wqa
  bf16_t* wqb_bf = (bf16_t*)(p + 25427968);
  bf16_t* wkvb_bf = (bf16_t*)(p + 34865152);
  bf16_t* wo_bf = (bf16_t*)(p + 39059456);
  float* qa_f32 = (float*)(p + 47448064);
  bf16_t* Kb = (bf16_t*)(p + 47448064);  // union with qa_f32
  bf16_t* qan_bf = (bf16_t*)(p + 72613888);
  bf16_t* Qb = (bf16_t*)(p + 85196800);
  char* r2 = p + 110362624;
  float* kvf_f32 = (float*)(r2);
  bf16_t* kvn_bf = (bf16_t*)(r2 + 9437184);
  bf16_t* Vtb = (bf16_t*)(r2 + 13631488);
  bf16_t* attn_bf = (bf16_t*)(r2 + 30408704);

  k_cvt_all<<<2048, 256, 0, stream>>>(x, wq_a, wq_b, wkv_a, wkv_b, wo, x_bf, wqa_bf,
                                      wqb_bf, wkva_bf, wkvb_bf, wo_bf);

  // merged: [q_a | kv_full] = x @ [wq_a; wkv_a]^T  [4096, 2112]  (17x32 tiles)
  k_gemm_bt<3><<<dim3(544), 256, 0, stream>>>(x_bf, wqa_bf, qa_f32, kvf_f32,
                                              nullptr, nullptr, nullptr, nullptr,
                                              NB * NS, QLORA + KVLORA + DROPE, ND);
  k_norm_post<<<NB * NS, 256, 0, stream>>>(qa_f32, q_norm_w, qan_bf, kvf_f32,
                                           kv_norm_w, fcos, fsin, kvn_bf, Kb);
  // dual (128^2 tiles, r15-proven): wq_b (RoPE -> Qb) + kv_b (K-nope + V^T)
  k_gemm_dual<<<dim3(1792), 256, 0, stream>>>(qan_bf, wqb_bf, Qb, fcos, fsin,
                                              kvn_bf, wkvb_bf, Kb, Vtb);
  // attention: 512 blocks x 256 threads, longest-first constant-sum pairing
  k_attn<<<dim3(512), 256, 0, stream>>>(Qb, Kb, Vtb, attn_bf);
  // out = attn @ wo^T  [4096,2048] f32  (16x32 tiles)
  k_gemm_bt<0><<<dim3(512), 256, 0, stream>>>(attn_bf, wo_bf, out, nullptr, nullptr,
                                              nullptr, nullptr, nullptr, NB * NS, ND,
                                              NH * DVDIM);
}

// Round 18
// 320.222 us; speedup vs baseline: 1.0401x; 1.0058x over previous
//
#include <hip/hip_runtime.h>
#include <hip/hip_bf16.h>

typedef __bf16 bf16_t;
typedef __bf16 bf16x8 __attribute__((ext_vector_type(8)));
typedef __bf16 bf16x4 __attribute__((ext_vector_type(4)));
typedef __bf16 bf16x2 __attribute__((ext_vector_type(2)));
typedef float  f32x4  __attribute__((ext_vector_type(4)));
typedef float  f32x16 __attribute__((ext_vector_type(16)));

#define NB 2
#define NS 2048
#define ND 2048
#define NH 16
#define QLORA 1536
#define KVLORA 512
#define DNOPE 128
#define DROPE 64
#define DVDIM 128
#define QKD 192

// 1/sqrt(192) * log2(e): Q is pre-scaled by this so QK^T lands in exp2 domain.
#define QSCALE 0.10411754f

#if __has_builtin(__builtin_amdgcn_exp2f)
#define EXP2F(x) __builtin_amdgcn_exp2f(x)
#else
#define EXP2F(x) __expf((x) * 0.69314718056f)
#endif
#if __has_builtin(__builtin_amdgcn_rcpf)
#define RCPF(x) __builtin_amdgcn_rcpf(x)
#else
#define RCPF(x) (1.0f / (x))
#endif

typedef __attribute__((address_space(3))) void as3_void;
typedef __attribute__((address_space(1))) const void as1_void;
__device__ __forceinline__ void gload16(const void* g, void* l) {
  __builtin_amdgcn_global_load_lds((as1_void*)g, (as3_void*)l, 16, 0, 0);
}

__device__ __forceinline__ int pack2(float a, float b) {
  bf16x2 t = {(bf16_t)a, (bf16_t)b};
  return __builtin_bit_cast(int, t);
}

// ---------------- fused f32 -> bf16 convert for all 6 tensors ----------------
__global__ __launch_bounds__(256) void k_cvt_all(
    const float* __restrict__ x, const float* __restrict__ wqa,
    const float* __restrict__ wqb, const float* __restrict__ wkva,
    const float* __restrict__ wkvb, const float* __restrict__ wo,
    bf16_t* __restrict__ xb, bf16_t* __restrict__ wqab, bf16_t* __restrict__ wqbb,
    bf16_t* __restrict__ wkvab, bf16_t* __restrict__ wkvbb, bf16_t* __restrict__ wob) {
  const int c0 = 2097152, c1 = 2883584, c2 = 4063232, c3 = 4358144, c4 = 4882432,
            c5 = 5931008;
  int i = blockIdx.x * 256 + threadIdx.x;
  for (; i < c5; i += gridDim.x * 256) {
    const float* src;
    bf16_t* dst;
    int off;
    if (i < c0) { src = x; dst = xb; off = i; }
    else if (i < c1) { src = wqa; dst = wqab; off = i - c0; }
    else if (i < c2) { src = wqb; dst = wqbb; off = i - c1; }
    else if (i < c3) { src = wkva; dst = wkvab; off = i - c2; }
    else if (i < c4) { src = wkvb; dst = wkvbb; off = i - c3; }
    else { src = wo; dst = wob; off = i - c4; }
    float4 v = reinterpret_cast<const float4*>(src)[off];
    bf16x4 o = {(bf16_t)v.x, (bf16_t)v.y, (bf16_t)v.z, (bf16_t)v.w};
    reinterpret_cast<bf16x4*>(dst)[off] = o;
  }
}

// ---------------- epilogue (shared) ----------------
template <int EPI>
__device__ __forceinline__ void gemm_epi(
    int col, int row0, const f32x4& a4,
    float* __restrict__ Cf, float* __restrict__ Cf2,
    bf16_t* __restrict__ Kout, bf16_t* __restrict__ Vtout,
    const float* __restrict__ fc, const float* __restrict__ fs, int N) {
  if (EPI == 1) {
    int h = col >> 8, rr = col & 255;
    int b = row0 >> 11, s0 = row0 & 2047;
    if (rr < DNOPE) {
#pragma unroll
      for (int r = 0; r < 4; ++r)
        Kout[(((size_t)(b * NH + h)) * NS + s0 + r) * QKD + rr] = (bf16_t)a4[r];
    } else {
      bf16x4 pv4 = {(bf16_t)a4[0], (bf16_t)a4[1], (bf16_t)a4[2], (bf16_t)a4[3]};
      *reinterpret_cast<bf16x4*>(
          &Vtout[(((size_t)(b * NH + h)) * DVDIM + (rr - DNOPE)) * NS + s0]) = pv4;
    }
  } else {
#pragma unroll
    for (int r = 0; r < 4; ++r) {
      int row = row0 + r;
      float v = a4[r];
      if (EPI == 0) {
        Cf[(size_t)row * N + col] = v;
      } else if (EPI == 2) {
        int h = col / 192;
        int d = col - h * 192;
        int b = row >> 11, s = row & 2047;
        float y = v;
        if (d >= DNOPE) {
          float pv = __shfl_xor(v, 1);
          int pp = ((d & ~1) - DNOPE) >> 1;
          float c = fc[s * 32 + pp], si = fs[s * 32 + pp];
          y = (col & 1) ? (pv * si + v * c) : (v * c - pv * si);
        }
        Kout[((size_t)(b * NH + h) * NS + s) * QKD + d] = (bf16_t)(y * QSCALE);
      } else {  // EPI 3
        if (col < QLORA) Cf[(size_t)row * QLORA + col] = v;
        else if (col < QLORA + KVLORA + DROPE)
          Cf2[(size_t)row * (KVLORA + DROPE) + (col - QLORA)] = v;
      }
    }
  }
}

// ---------------- GEMM core 128x128 (4 waves, r10-proven; 64KB -> 2 blocks/CU) ----
template <int EPI>
__device__ __forceinline__ void gemm_core(
    int rank, bf16_t* As, bf16_t* Bs,
    const bf16_t* __restrict__ A, const bf16_t* __restrict__ Bw,
    float* __restrict__ Cf, float* __restrict__ Cf2,
    bf16_t* __restrict__ Kout, bf16_t* __restrict__ Vtout,
    const float* __restrict__ fc, const float* __restrict__ fs,
    int M, int N, int K) {
  const int tid = threadIdx.x;
  const int lane = tid & 63;
  const int wave = tid >> 6;
  const int wm = (wave >> 1) * 64, wn = (wave & 1) * 64;
  const int nxt = (N + 127) >> 7;
  const int by = rank / nxt, bx = rank - by * nxt;
  const int m0 = by * 128, n0 = bx * 128;
  const int l15 = lane & 15, l4 = lane >> 4;
  const int srow = lane >> 3;
  const int scol = ((lane & 7) ^ srow) * 8;

  const f32x4 Z4 = {0.f, 0.f, 0.f, 0.f};
  f32x4 acc[4][4];
#pragma unroll
  for (int i = 0; i < 4; ++i)
#pragma unroll
    for (int j = 0; j < 4; ++j) acc[i][j] = Z4;

  auto stage = [&](int buf, int k0) {
#pragma unroll
    for (int c = 0; c < 4; ++c) {
      int chunk = c * 4 + wave;
      int row = chunk * 8 + srow;
      gload16(A + (size_t)(m0 + row) * K + k0 + scol, &As[buf * 8192 + chunk * 512]);
      gload16(Bw + (size_t)(n0 + row) * K + k0 + scol, &Bs[buf * 8192 + chunk * 512]);
    }
  };

  const int nk = K >> 6;
  stage(0, 0);
  int cur = 0;
#pragma unroll 1
  for (int t = 0; t < nk; ++t) {
    if (t + 1 < nk) {
      stage(cur ^ 1, (t + 1) * 64);
      asm volatile("s_waitcnt vmcnt(8)" ::: "memory");
    } else {
      asm volatile("s_waitcnt vmcnt(0)" ::: "memory");
    }
    __builtin_amdgcn_sched_barrier(0);
    __builtin_amdgcn_s_barrier();
    __builtin_amdgcn_sched_barrier(0);
#pragma unroll
    for (int ks = 0; ks < 2; ++ks) {
      int kc = ks * 4 + l4;
      int pc = (kc ^ (l15 & 7)) * 8;
      bf16x8 af[4], bfr[4];
#pragma unroll
      for (int f = 0; f < 4; ++f) {
        af[f] = *reinterpret_cast<const bf16x8*>(
            &As[cur * 8192 + (wm + f * 16 + l15) * 64 + pc]);
        bfr[f] = *reinterpret_cast<const bf16x8*>(
            &Bs[cur * 8192 + (wn + f * 16 + l15) * 64 + pc]);
      }
#pragma unroll
      for (int fi = 0; fi < 4; ++fi)
#pragma unroll
        for (int fj = 0; fj < 4; ++fj)
          acc[fi][fj] = __builtin_amdgcn_mfma_f32_16x16x32_bf16(af[fi], bfr[fj], acc[fi][fj], 0, 0, 0);
    }
    __builtin_amdgcn_sched_barrier(0);
    __builtin_amdgcn_s_barrier();
    cur ^= 1;
  }

#pragma unroll
  for (int fi = 0; fi < 4; ++fi)
#pragma unroll
    for (int fj = 0; fj < 4; ++fj)
      gemm_epi<EPI>(n0 + wn + fj * 16 + l15, m0 + wm + fi * 16 + l4 * 4, acc[fi][fj],
                    Cf, Cf2, Kout, Vtout, fc, fs, N);
}

// ---------------- GEMM core 256x256 fat-wave (8 waves x 128Mx64N, acc[8][4]) ----
// Single-barrier deep pipeline: per K-tile {vmcnt(0) own loads -> s_barrier ->
// issue stage(t+1) -> compute(t)}. stage(t+1) flies under compute(t); only
// tile-t loads are outstanding at the wait. reads/MFMA 0.375 vs 0.5 at 128^2.
template <int EPI>
__device__ __forceinline__ void gemm_core256f(
    int rank, bf16_t* As, bf16_t* Bs,
    const bf16_t* __restrict__ A, const bf16_t* __restrict__ Bw,
    bf16_t* __restrict__ Kout, bf16_t* __restrict__ Vtout,
    const float* __restrict__ fc, const float* __restrict__ fs,
    int N, int K) {
  const int tid = threadIdx.x;   // 0..511
  const int lane = tid & 63;
  const int wave = tid >> 6;     // 0..7
  const int wm = (wave >> 2) * 128;  // 0,128
  const int wn = (wave & 3) * 64;    // 0..192
  const int nxt = N >> 8;
  const int by = rank / nxt, bx = rank - by * nxt;
  const int m0 = by * 256, n0 = bx * 256;
  const int l15 = lane & 15, l4 = lane >> 4;
  const int srow = lane >> 3;
  const int scol = ((lane & 7) ^ srow) * 8;

  const f32x4 Z4 = {0.f, 0.f, 0.f, 0.f};
  f32x4 acc[8][4];
#pragma unroll
  for (int i = 0; i < 8; ++i)
#pragma unroll
    for (int j = 0; j < 4; ++j) acc[i][j] = Z4;

  auto stage = [&](int buf, int k0) {
#pragma unroll
    for (int c = 0; c < 4; ++c) {
      int chunk = c * 8 + wave;       // 0..31 (A and B each 32 chunks of 8 rows)
      int row = chunk * 8 + srow;
      gload16(A + (size_t)(m0 + row) * K + k0 + scol, &As[buf * 16384 + chunk * 512]);
      gload16(Bw + (size_t)(n0 + row) * K + k0 + scol, &Bs[buf * 16384 + chunk * 512]);
    }
  };

  const int nk = K >> 6;
  stage(0, 0);
  int cur = 0;
#pragma unroll 1
  for (int t = 0; t < nk; ++t) {
    asm volatile("s_waitcnt vmcnt(0)" ::: "memory");  // my tile-t loads (only outstanding)
    __builtin_amdgcn_sched_barrier(0);
    __builtin_amdgcn_s_barrier();  // all tile-t loads landed; all waves done reading buf^1
    __builtin_amdgcn_sched_barrier(0);
    if (t + 1 < nk) stage(cur ^ 1, (t + 1) * 64);  // overlaps with compute below
#pragma unroll
    for (int ks = 0; ks < 2; ++ks) {
      int kc = ks * 4 + l4;
      int pc = (kc ^ (l15 & 7)) * 8;
      bf16x8 af[8], bfr[4];
#pragma unroll
      for (int f = 0; f < 8; ++f)
        af[f] = *reinterpret_cast<const bf16x8*>(
            &As[cur * 16384 + (wm + f * 16 + l15) * 64 + pc]);
#pragma unroll
      for (int f = 0; f < 4; ++f)
        bfr[f] = *reinterpret_cast<const bf16x8*>(
            &Bs[cur * 16384 + (wn + f * 16 + l15) * 64 + pc]);
#pragma unroll
      for (int fi = 0; fi < 8; ++fi)
#pragma unroll
        for (int fj = 0; fj < 4; ++fj)
          acc[fi][fj] = __builtin_amdgcn_mfma_f32_16x16x32_bf16(af[fi], bfr[fj], acc[fi][fj], 0, 0, 0);
    }
    cur ^= 1;
  }

#pragma unroll
  for (int fi = 0; fi < 8; ++fi)
#pragma unroll
    for (int fj = 0; fj < 4; ++fj)
      gemm_epi<EPI>(n0 + wn + fj * 16 + l15, m0 + wm + fi * 16 + l4 * 4, acc[fi][fj],
                    nullptr, nullptr, Kout, Vtout, fc, fs, N);
}

// standalone GEMM wrapper (128^2, XCD-chunked swizzle)
template <int EPI>
__global__ __launch_bounds__(256) void k_gemm_bt(
    const bf16_t* __restrict__ A, const bf16_t* __restrict__ Bw,
    float* __restrict__ Cf, float* __restrict__ Cf2,
    bf16_t* __restrict__ Kout, bf16_t* __restrict__ Vtout,
    const float* __restrict__ fc, const float* __restrict__ fs,
    int M, int N, int K) {
  __shared__ bf16_t As[2 * 128 * 64];
  __shared__ bf16_t Bs[2 * 128 * 64];
  const int per = gridDim.x >> 3;
  const int rank = (blockIdx.x & 7) * per + (blockIdx.x >> 3);
  gemm_core<EPI>(rank, As, Bs, A, Bw, Cf, Cf2, Kout, Vtout, fc, fs, M, N, K);
}

// dual GEMM, 256^2 fat-wave: blocks [0,192) -> wq_b (EPI2); [192,448) -> kv_b
// (EPI1). 128KB LDS -> 1 block/CU; single-barrier deep pipeline supplies overlap.
__global__ __launch_bounds__(512, 2) void k_gemm_dual(
    const bf16_t* __restrict__ A2, const bf16_t* __restrict__ B2,
    bf16_t* __restrict__ Qb, const float* __restrict__ fc,
    const float* __restrict__ fs, const bf16_t* __restrict__ A1,
    const bf16_t* __restrict__ B1, bf16_t* __restrict__ Kout,
    bf16_t* __restrict__ Vtout) {
  __shared__ bf16_t As[2 * 256 * 64];
  __shared__ bf16_t Bs[2 * 256 * 64];
  const int G2 = 192;  // wq_b tiles: 16M x 12N
  if ((int)blockIdx.x < G2) {
    int id = blockIdx.x;
    int rank = (id & 7) * (G2 >> 3) + (id >> 3);
    gemm_core256f<2>(rank, As, Bs, A2, B2, Qb, nullptr, fc, fs, NH * QKD, QLORA);
  } else {
    int id = blockIdx.x - G2;  // kv_b tiles: 16M x 16N = 256
    int rank = (id & 7) * 32 + (id >> 3);
    gemm_core256f<1>(rank, As, Bs, A1, B1, Kout, Vtout, nullptr, nullptr,
                     NH * (DNOPE + DVDIM), KVLORA);
  }
}

// ---------------- merged per-token post: RMS-norm(q_a) + RMS-norm(kv)+RoPE ----
__global__ __launch_bounds__(256) void k_norm_post(
    const float* __restrict__ qa, const float* __restrict__ qw,
    bf16_t* __restrict__ qan, const float* __restrict__ kvf,
    const float* __restrict__ kw, const float* __restrict__ fc,
    const float* __restrict__ fs, bf16_t* __restrict__ kvn,
    bf16_t* __restrict__ Kb) {
  int row = blockIdx.x;  // token
  __shared__ float red[4];
  {
    const float* rp = qa + (size_t)row * QLORA;
    float ss = 0.f;
    for (int c = threadIdx.x * 4; c < QLORA; c += 1024) {
      float4 v = *reinterpret_cast<const float4*>(rp + c);
      ss += v.x * v.x + v.y * v.y + v.z * v.z + v.w * v.w;
    }
#pragma unroll
    for (int m = 32; m; m >>= 1) ss += __shfl_xor(ss, m);
    if ((threadIdx.x & 63) == 0) red[threadIdx.x >> 6] = ss;
    __syncthreads();
    float tot = red[0] + red[1] + red[2] + red[3];
    float rs = rsqrtf(tot / (float)QLORA + 1e-6f);
    for (int c = threadIdx.x * 4; c < QLORA; c += 1024) {
      float4 v = *reinterpret_cast<const float4*>(rp + c);
      bf16x4 o = {(bf16_t)(v.x * rs * qw[c]), (bf16_t)(v.y * rs * qw[c + 1]),
                  (bf16_t)(v.z * rs * qw[c + 2]), (bf16_t)(v.w * rs * qw[c + 3])};
      *reinterpret_cast<bf16x4*>(qan + (size_t)row * QLORA + c) = o;
    }
  }
  __syncthreads();
  const float* rp = kvf + (size_t)row * (KVLORA + DROPE);
  float ss = 0.f;
  float4 v = {0.f, 0.f, 0.f, 0.f};
  if (threadIdx.x < 128) {
    v = reinterpret_cast<const float4*>(rp)[threadIdx.x];
    ss = v.x * v.x + v.y * v.y + v.z * v.z + v.w * v.w;
  }
#pragma unroll
  for (int m = 32; m; m >>= 1) ss += __shfl_xor(ss, m);
  if ((threadIdx.x & 63) == 0) red[threadIdx.x >> 6] = ss;
  __syncthreads();
  float tot = red[0] + red[1] + red[2] + red[3];
  float rs = rsqrtf(tot / (float)KVLORA + 1e-6f);
  if (threadIdx.x < 128) {
    int c = threadIdx.x * 4;
    bf16x4 o = {(bf16_t)(v.x * rs * kw[c]), (bf16_t)(v.y * rs * kw[c + 1]),
                (bf16_t)(v.z * rs * kw[c + 2]), (bf16_t)(v.w * rs * kw[c + 3])};
    *reinterpret_cast<bf16x4*>(kvn + (size_t)row * KVLORA + c) = o;
  }
  int b = row >> 11, s = row & 2047;
  if (threadIdx.x < 32) {
    int p = threadIdx.x;
    float x0 = rp[KVLORA + 2 * p], x1 = rp[KVLORA + 2 * p + 1];
    float c = fc[s * 32 + p], si = fs[s * 32 + p];
    float yr = x0 * c - x1 * si, yi = x0 * si + x1 * c;
    bf16_t br = (bf16_t)yr, bi = (bf16_t)yi;
    for (int h = 0; h < NH; ++h) {
      size_t ob = ((size_t)(b * NH + h) * NS + s) * QKD + DNOPE;
      Kb[ob + 2 * p] = br;
      Kb[ob + 2 * p + 1] = bi;
    }
  }
}

// ---------------- flash attention: 32x32 MFMA, swapped QK^T, in-register softmax ----
// r11-exact (proven 94us): 4 waves x 32 q (QBLK=128), KVBLK=64, K/V dbuf LDS 80KB,
// gload_lds prefetch + counted vmcnt(10) + raw s_barriers. At LDS-BW cap (~19%).
__global__ __launch_bounds__(256, 2) void k_attn(const bf16_t* __restrict__ Qb,
                                                 const bf16_t* __restrict__ Kb,
                                                 const bf16_t* __restrict__ Vtb,
                                                 bf16_t* __restrict__ Ao) {
  __shared__ bf16x8 Ks8[2][64 * 24];
  __shared__ bf16x8 Vs8[2][128 * 8];
  const int id = blockIdx.x;
  const int bh = id & 31;
  const int aa = (id >> 5) & 7;
  const int qt = (id >> 8) ? aa : (15 - aa);
  const int b = bh >> 4, h = bh & 15;
  const int tid = threadIdx.x;
  const int lane = tid & 63, wave = tid >> 6;
  const int l31 = lane & 31, hi = lane >> 5;
  const int q0w = qt * 128 + wave * 32;
  const int qg = q0w + l31;  // this lane's q row
  const int c4 = hi * 4;
  const int ntiles = 2 * qt + 2;
  const size_t bhNS = (size_t)bh * NS;

  const bf16_t* KbB = Kb + bhNS * QKD;
  const bf16_t* VtB = Vtb + (size_t)bh * DVDIM * NS;
  int koff[6], voff[4];
#pragma unroll
  for (int i = 0; i < 6; ++i) {
    int p = tid + i * 256;
    int row = p / 24, pc = p % 24;
    int lc = (pc & ~7) | ((pc ^ row) & 7);
    koff[i] = row * QKD + lc * 8;
  }
#pragma unroll
  for (int i = 0; i < 4; ++i) {
    int p = tid + i * 256;
    int row = p >> 3, pc = p & 7;
    int lc = pc ^ (row & 7);
    voff[i] = row * NS + lc * 8;
  }

  auto stageKV = [&](int buf, int kv0) {
    const bf16_t* ksrc = KbB + kv0 * QKD;
    const bf16_t* vsrc = VtB + kv0;
    bf16x8* kdst = &Ks8[buf][wave * 64];
    bf16x8* vdst = &Vs8[buf][wave * 64];
#pragma unroll
    for (int i = 0; i < 6; ++i) gload16(ksrc + koff[i], kdst + i * 256);
#pragma unroll
    for (int i = 0; i < 4; ++i) gload16(vsrc + voff[i], vdst + i * 256);
  };

  bf16x8 qf[12];
  {
    const bf16_t* qp = Qb + (bhNS + qg) * QKD + hi * 8;
#pragma unroll
    for (int ks = 0; ks < 12; ++ks)
      qf[ks] = *reinterpret_cast<const bf16x8*>(qp + ks * 16);
  }

  f32x16 oacc[4];
#pragma unroll
  for (int d = 0; d < 4; ++d) oacc[d] = {};
  float mrun = -3e38f, lrun = 0.f;

  stageKV(0, 0);
  int cur = 0;

#pragma unroll 1
  for (int kt = 0; kt < ntiles; ++kt) {
    const int kv0 = kt * 64;
    if (kt + 1 < ntiles) {
      stageKV(cur ^ 1, kv0 + 64);
      asm volatile("s_waitcnt vmcnt(10)" ::: "memory");
    } else {
      asm volatile("s_waitcnt vmcnt(0)" ::: "memory");
    }
    __builtin_amdgcn_sched_barrier(0);
    __builtin_amdgcn_s_barrier();  // all waves: tile kt resident in LDS[cur]
    __builtin_amdgcn_sched_barrier(0);

    if (kv0 <= q0w + 31) {
      f32x16 sacc[2];
      sacc[0] = {};
      sacc[1] = {};
#pragma unroll
      for (int ks = 0; ks < 12; ++ks) {
#pragma unroll
        for (int kh = 0; kh < 2; ++kh) {
          int row = kh * 32 + l31;
          int c = ks * 2 + hi;
          int pc = (c & ~7) | ((c ^ row) & 7);
          sacc[kh] = __builtin_amdgcn_mfma_f32_32x32x16_bf16(Ks8[cur][row * 24 + pc],
                                                             qf[ks], sacc[kh], 0, 0, 0);
        }
      }

      const bool diag = (kv0 + 63 > q0w);
      float mloc = -3e38f;
#pragma unroll
      for (int kh = 0; kh < 2; ++kh)
#pragma unroll
        for (int rg = 0; rg < 16; ++rg) {
          float s = sacc[kh][rg];
          if (diag) {
            int kg = kv0 + kh * 32 + (rg & 3) + 8 * (rg >> 2) + c4;
            if (kg > qg) s = -3e38f;
            sacc[kh][rg] = s;
          }
          mloc = fmaxf(mloc, s);
        }
      mloc = fmaxf(mloc, __shfl_xor(mloc, 32));

      if (!__all(mloc <= mrun)) {
        float mn = fmaxf(mrun, mloc);
        float fac = EXP2F(mrun - mn);
        mrun = mn;
        lrun *= fac;
#pragma unroll
        for (int d = 0; d < 4; ++d)
#pragma unroll
          for (int rg = 0; rg < 16; ++rg) oacc[d][rg] *= fac;
      }

      float rsum = 0.f;
      int W[8][2];
#pragma unroll
      for (int kh = 0; kh < 2; ++kh)
#pragma unroll
        for (int g = 0; g < 4; ++g) {
          float p0 = EXP2F(sacc[kh][4 * g + 0] - mrun);
          float p1 = EXP2F(sacc[kh][4 * g + 1] - mrun);
          float p2 = EXP2F(sacc[kh][4 * g + 2] - mrun);
          float p3 = EXP2F(sacc[kh][4 * g + 3] - mrun);
          rsum += (p0 + p1) + (p2 + p3);
          W[kh * 4 + g][0] = pack2(p0, p1);
          W[kh * 4 + g][1] = pack2(p2, p3);
        }
      rsum += __shfl_xor(rsum, 32);
      lrun += rsum;

      bf16x8 pa[4];
#pragma unroll
      for (int pks = 0; pks < 4; ++pks) {
        int kh = pks >> 1, G0 = (pks & 1) * 2;
        int a0 = W[kh * 4 + G0][0], a1 = W[kh * 4 + G0][1];
        int b0 = W[kh * 4 + G0 + 1][0], b1 = W[kh * 4 + G0 + 1][1];
        int own0 = hi ? b0 : a0, own1 = hi ? b1 : a1;
        int oth0 = hi ? a0 : b0, oth1 = hi ? a1 : b1;
        int rc0 = __shfl_xor(oth0, 32), rc1 = __shfl_xor(oth1, 32);
        int4 wv;
        wv.x = hi ? rc0 : own0;
        wv.y = hi ? rc1 : own1;
        wv.z = hi ? own0 : rc0;
        wv.w = hi ? own1 : rc1;
        pa[pks] = __builtin_bit_cast(bf16x8, wv);
      }

#pragma unroll
      for (int pks = 0; pks < 4; ++pks)
#pragma unroll
        for (int dvt = 0; dvt < 4; ++dvt) {
          int row = dvt * 32 + l31;
          int pc = (pks * 2 + hi) ^ (row & 7);
          oacc[dvt] = __builtin_amdgcn_mfma_f32_32x32x16_bf16(Vs8[cur][row * 8 + pc],
                                                              pa[pks], oacc[dvt], 0, 0, 0);
        }
    }

    __builtin_amdgcn_sched_barrier(0);
    __builtin_amdgcn_s_barrier();  // all waves done reading LDS[cur]
    cur ^= 1;
  }

  // epilogue: O^T -> Ao[token][h*128+dv]
  float lr = RCPF(lrun);
  bf16_t* base = Ao + ((size_t)(b * NS) + qg) * (NH * DVDIM) + h * DVDIM;
#pragma unroll
  for (int dvt = 0; dvt < 4; ++dvt)
#pragma unroll
    for (int rg4 = 0; rg4 < 4; ++rg4) {
      int dv0 = dvt * 32 + 8 * rg4 + c4;
      bf16x4 o = {(bf16_t)(oacc[dvt][rg4 * 4 + 0] * lr),
                  (bf16_t)(oacc[dvt][rg4 * 4 + 1] * lr),
                  (bf16_t)(oacc[dvt][rg4 * 4 + 2] * lr),
                  (bf16_t)(oacc[dvt][rg4 * 4 + 3] * lr)};
      *reinterpret_cast<bf16x4*>(base + dv0) = o;
    }
}

// ---------------- launch ----------------
extern "C" void kernel_launch(void* const* d_in, const int* in_sizes, int n_in,
                              void* d_out, int out_size, void* d_ws, size_t ws_size,
                              hipStream_t stream) {
  (void)in_sizes; (void)n_in; (void)out_size; (void)ws_size;
  const float* x = (const float*)d_in[0];
  const float* fcos = (const float*)d_in[1];
  const float* fsin = (const float*)d_in[2];
  const float* wq_a = (const float*)d_in[4];
  const float* q_norm_w = (const float*)d_in[5];
  const float* wq_b = (const float*)d_in[6];
  const float* wkv_a = (const float*)d_in[7];
  const float* kv_norm_w = (const float*)d_in[8];
  const float* wkv_b = (const float*)d_in[9];
  const float* wo = (const float*)d_in[10];
  float* out = (float*)d_out;

  char* p = (char*)d_ws;
  bf16_t* x_bf = (bf16_t*)(p);
  bf16_t* wqa_bf = (bf16_t*)(p + 16777216);
  bf16_t* wkva_bf = (bf16_t*)(p + 23068672);  // contiguous with wqa
  bf16_t* wqb_bf = (bf16_t*)(p + 25427968);
  bf16_t* wkvb_bf = (bf16_t*)(p + 34865152);
  bf16_t* wo_bf = (bf16_t*)(p + 39059456);
  float* qa_f32 = (float*)(p + 47448064);
  bf16_t* Kb = (bf16_t*)(p + 47448064);  // union with qa_f32
  bf16_t* qan_bf = (bf16_t*)(p + 72613888);
  bf16_t* Qb = (bf16_t*)(p + 85196800);
  char* r2 = p + 110362624;
  float* kvf_f32 = (float*)(r2);
  bf16_t* kvn_bf = (bf16_t*)(r2 + 9437184);
  bf16_t* Vtb = (bf16_t*)(r2 + 13631488);
  bf16_t* attn_bf = (bf16_t*)(r2 + 30408704);

  k_cvt_all<<<2048, 256, 0, stream>>>(x, wq_a, wq_b, wkv_a, wkv_b, wo, x_bf, wqa_bf,
                                      wqb_bf, wkva_bf, wkvb_bf, wo_bf);

  // merged: [q_a | kv_full] = x @ [wq_a; wkv_a]^T  [4096, 2112]  (17x32 tiles)
  k_gemm_bt<3><<<dim3(544), 256, 0, stream>>>(x_bf, wqa_bf, qa_f32, kvf_f32,
                                              nullptr, nullptr, nullptr, nullptr,
                                              NB * NS, QLORA + KVLORA + DROPE, ND);
  k_norm_post<<<NB * NS, 256, 0, stream>>>(qa_f32, q_norm_w, qan_bf, kvf_f32,
                                           kv_norm_w, fcos, fsin, kvn_bf, Kb);
  // dual (256^2 fat-wave): wq_b (RoPE -> Qb) + kv_b (K-nope + V^T)
  k_gemm_dual<<<dim3(448), 512, 0, stream>>>(qan_bf, wqb_bf, Qb, fcos, fsin,
                                             kvn_bf, wkvb_bf, Kb, Vtb);
  // attention: 512 blocks x 256 threads, longest-first constant-sum pairing
  k_attn<<<dim3(512), 256, 0, stream>>>(Qb, Kb, Vtb, attn_bf);
  // out = attn @ wo^T  [4096,2048] f32  (16x32 tiles)
  k_gemm_bt<0><<<dim3(512), 256, 0, stream>>>(attn_bf, wo_bf, out, nullptr, nullptr,
                                              nullptr, nullptr, nullptr, NB * NS, ND,
                                              NH * DVDIM);
}